// Round 1
// baseline (139.643 us; speedup 1.0000x reference)
//
#include <hip/hip_runtime.h>

// r[i,j] = sum_{ii,ij} img[ii,ij] * K[i-ii, j-ij],  K[u,v] = 1/((u+pos0)^2+(v+pos1)^2)
// img: 256x512 f32, pos: 2 f32, out: 32x256 f32.

constexpr int H  = 256;
constexpr int W  = 512;
constexpr int OH = 32;
constexpr int OW = 256;
constexpr int KW = 768;   // padded K row: word b <-> v = b - 512, valid used range b in [1,767]
constexpr int NII = 4;    // img rows per block
constexpr int BLK = 128;  // 2 waves

__global__ __launch_bounds__(BLK) void corr_kernel(
    const float* __restrict__ img, const float* __restrict__ pos,
    float* __restrict__ out)
{
    __shared__ float Ks[NII][KW];
    __shared__ float imgS[NII][W];
    __shared__ float red[2][OW];

    const int i   = blockIdx.x;        // output row
    const int ii0 = blockIdx.y * NII;  // first img row of this block
    const int tid = threadIdx.x;

    const float pos0 = pos[0];
    const float pos1 = pos[1];

    // ---- build K rows in LDS: Ks[r][b] = 1/(dx_r^2 + dy_b^2), dy_b = (b-512)+pos1
    for (int r = 0; r < NII; ++r) {
        const float dx  = (float)(i - (ii0 + r)) + pos0;
        const float dx2 = dx * dx;
        for (int b = tid; b < KW; b += BLK) {
            const float dy = (float)(b - 512) + pos1;
            Ks[r][b] = 1.0f / (dx2 + dy * dy);
        }
    }
    // ---- stage img rows
    for (int r = 0; r < NII; ++r) {
        const int row = ii0 + r;
        for (int c = tid; c < W; c += BLK)
            imgS[r][c] = img[row * W + c];
    }
    __syncthreads();

    const int w    = tid >> 6;   // wave 0..1
    const int lane = tid & 63;   // lane: owns j = 4*lane + p

    float acc[4] = {0.f, 0.f, 0.f, 0.f};

    // each wave processes rows {w, w+2}
    for (int rr = 0; rr < NII; rr += 2) {
        const int r = rr + w;
        const float* __restrict__ krow = &Ks[r][0];
        const float* __restrict__ irow = &imgS[r][0];

        const int base = 4 * lane + 508;  // word index of window-A at c=0

        float4 kA = *(const float4*)(krow + base);      // words [base-c .. +3]
        float4 kB = *(const float4*)(krow + base + 4);  // words [base-c+4 .. +7]

        auto do_chunk = [&](const float4& iv, const float4& a, const float4& b) {
            const float* ka = (const float*)&a;
            const float* kb = (const float*)&b;
            const float* iw = (const float*)&iv;
#pragma unroll
            for (int p = 0; p < 4; ++p) {
#pragma unroll
                for (int s = 0; s < 4; ++s) {
                    const int o = 4 + p - s;            // window offset, in [1,7]
                    const float kv = (o < 4) ? ka[o] : kb[o - 4];
                    acc[p] = fmaf(iw[s], kv, acc[p]);
                }
            }
        };

#pragma unroll 4
        for (int c = 0; c < W - 4; c += 4) {
            const float4 iv = *(const float4*)(irow + c);   // broadcast (uniform addr)
            do_chunk(iv, kA, kB);
            kB = kA;                                        // slide window down by 4
            kA = *(const float4*)(krow + (base - c - 4));   // A(c+4); >= word 0 always
        }
        {   // final chunk c = W-4 = 508
            const float4 iv = *(const float4*)(irow + (W - 4));
            do_chunk(iv, kA, kB);
        }
    }

    // ---- combine the 2 waves' partials, add to global
    red[w][4 * lane + 0] = acc[0];
    red[w][4 * lane + 1] = acc[1];
    red[w][4 * lane + 2] = acc[2];
    red[w][4 * lane + 3] = acc[3];
    __syncthreads();

    for (int j = tid; j < OW; j += BLK)
        atomicAdd(&out[i * OW + j], red[0][j] + red[1][j]);
}

extern "C" void kernel_launch(void* const* d_in, const int* in_sizes, int n_in,
                              void* d_out, int out_size, void* d_ws, size_t ws_size,
                              hipStream_t stream) {
    const float* img = (const float*)d_in[0];
    const float* pos = (const float*)d_in[1];
    float* out = (float*)d_out;

    hipMemsetAsync(out, 0, (size_t)out_size * sizeof(float), stream);

    dim3 grid(OH, H / NII);   // 32 x 64
    corr_kernel<<<grid, BLK, 0, stream>>>(img, pos, out);
}

// Round 3
// 91.021 us; speedup vs baseline: 1.5342x; 1.5342x over previous
//
#include <hip/hip_runtime.h>

// r[i,j] = sum_{ii,ij} img[ii,ij] * K[i-ii, j-ij],  K[u,v] = 1/((u+pos0)^2+(v+pos1)^2)
// img: 256x512 f32, pos: 2 f32, out: 32x256 f32.
//
// Round-2 structure (resubmitted after GPU acquisition timeout):
//  - lane L = tid&31 owns outputs j = 8L+p (p=0..7); half = tid>>5&1 selects img row
//  - K row per (i,ii) staged in LDS with a segment-rotation swizzle so the
//    stride-32B sliding-window ds_read_b128 is conflict-free
//  - img read directly from global (per-half-uniform float4, L1/L2 resident)
//  - grid 32x32 = 1024 blocks, 33.8KB LDS -> 4 blocks/CU, all co-resident

constexpr int H  = 256;
constexpr int W  = 512;
constexpr int OH = 32;
constexpr int OW = 256;
constexpr int NR = 8;     // img rows per block (4 waves x 2 halves)
constexpr int KROW = 800; // swizzled K row: word x <-> v = x-516, 25 segments of 32
constexpr int BLK = 256;

// segment-rotation swizzle: word x -> LDS word position (within one K row)
__device__ __forceinline__ int swz(int x) {
    const int seg = x >> 5;
    const int off = x & 31;
    return (seg << 5) | ((off + ((seg & 7) << 2)) & 31);
}

__global__ __launch_bounds__(BLK, 4) void corr2(
    const float* __restrict__ img, const float* __restrict__ pos,
    float* __restrict__ out)
{
    __shared__ float Ks[NR * KROW];
    __shared__ float red[NR][OW];

    const int i   = blockIdx.x;        // output row
    const int ii0 = blockIdx.y * NR;   // first img row of this block
    const int tid = threadIdx.x;

    const float pos0 = pos[0];
    const float pos1 = pos[1];

    // ---- build swizzled K rows: K word x holds 1/(dx^2 + (x-516+pos1)^2)
    for (int rg = 0; rg < NR; ++rg) {
        const float dx  = (float)(i - (ii0 + rg)) + pos0;
        const float dx2 = dx * dx;
        for (int x = tid; x < KROW; x += BLK) {
            const float dy = (float)(x - 516) + pos1;
            Ks[rg * KROW + swz(x)] = 1.0f / (dx2 + dy * dy);
        }
    }
    __syncthreads();

    const int wv  = tid >> 6;          // wave 0..3
    const int L   = tid & 31;          // lane-in-half: owns j = 8L+p
    const int hf  = (tid >> 5) & 1;    // half selects row
    const int rg  = wv * 2 + hf;       // row group 0..7
    const int row = ii0 + rg;

    const float4* __restrict__ ip = (const float4*)(img + row * W);
    const int kbase = rg * KROW;

    float acc[8] = {0.f,0.f,0.f,0.f,0.f,0.f,0.f,0.f};

    // sliding window: at chunk c (cols c..c+3), window base word A = 8L+512-c,
    // needed offsets d = p-s+4 in [1,11] -> quads Q0=[A..A+3],Q1=[A+4..],Q2=[A+8..]
    int wq = 8 * L + 512;              // = A(c=0)
    float4 qa = *(const float4*)&Ks[kbase + swz(wq)];
    float4 qb = *(const float4*)&Ks[kbase + swz(wq + 4)];
    float4 qc = *(const float4*)&Ks[kbase + swz(wq + 8)];

    int ci = 0;                        // chunk index = c/4

#define STEP(Q0, Q1, Q2)                                                      \
    do {                                                                      \
        const float4 iv = ip[ci];                                             \
        _Pragma("unroll")                                                     \
        for (int p = 0; p < 8; ++p) {                                         \
            _Pragma("unroll")                                                 \
            for (int s = 0; s < 4; ++s) {                                     \
                const int d = p - s + 4; /* compile-time after unroll */      \
                const float kv = (d < 4) ? ((const float*)&(Q0))[d]           \
                               : (d < 8) ? ((const float*)&(Q1))[d - 4]       \
                                         : ((const float*)&(Q2))[d - 8];      \
                acc[p] = fmaf(((const float*)&iv)[s], kv, acc[p]);            \
            }                                                                 \
        }                                                                     \
        wq -= 4; ++ci;                                                        \
        /* load next (lowest) quad into the retiring register */             \
        (Q2) = *(const float4*)&Ks[kbase + swz(wq)];                          \
    } while (0)

#pragma unroll 1
    for (int t = 0; t < 42; ++t) {     // 3 steps/iter, window roles rotate
        STEP(qa, qb, qc);
        STEP(qc, qa, qb);
        STEP(qb, qc, qa);
    }
    STEP(qa, qb, qc);                  // 127th
    STEP(qc, qa, qb);                  // 128th (its prefetch load is in-bounds)
#undef STEP

    // ---- reduce 8 row-groups, add to global
#pragma unroll
    for (int p = 0; p < 8; ++p)
        red[rg][8 * L + p] = acc[p];
    __syncthreads();

    {
        const int j = tid;             // BLK == OW
        float s = 0.f;
#pragma unroll
        for (int r = 0; r < NR; ++r) s += red[r][j];
        atomicAdd(&out[i * OW + j], s);
    }
}

extern "C" void kernel_launch(void* const* d_in, const int* in_sizes, int n_in,
                              void* d_out, int out_size, void* d_ws, size_t ws_size,
                              hipStream_t stream) {
    const float* img = (const float*)d_in[0];
    const float* pos = (const float*)d_in[1];
    float* out = (float*)d_out;

    hipMemsetAsync(out, 0, (size_t)out_size * sizeof(float), stream);

    dim3 grid(OH, H / NR);             // 32 x 32 = 1024 blocks, all co-resident
    corr2<<<grid, BLK, 0, stream>>>(img, pos, out);
}

// Round 4
// 87.578 us; speedup vs baseline: 1.5945x; 1.0393x over previous
//
#include <hip/hip_runtime.h>

// r[i,j] = sum_{ii,ij} img[ii,ij] * K[i-ii, j-ij],  K[u,v] = 1/((u+pos0)^2+(v+pos1)^2)
// img: 256x512 f32, pos: 2 f32, out: 32x256 f32.
//
// Round-4: J=16 register tile -> 64 FMAs per ds_read_b128 (LDS demand hidden
// under VALU even if quad-aligned b128 conflicts persist).
//  - 16 lanes cover all 256 outputs (lane M owns j = 16M+p, p=0..15)
//  - block = 256 thr = 16 groups of 16 lanes: group G -> (img row rg=G>>1, col half h=G&1)
//  - K row per (i,ii) staged in LDS with quad-rotation swizzle (as round 3)
//  - 8-slot rotating float4 window, fresh quad read 3 steps ahead
//  - epilogue: shfl_xor(16/32) folds 4 groups/wave, red[4][256] in LDS, 1 atomic/j

constexpr int H  = 256;
constexpr int W  = 512;
constexpr int OH = 32;
constexpr int OW = 256;
constexpr int NR   = 8;    // img rows per block
constexpr int KROW = 800;  // K row words; word t <-> v = t - 512, used t in [0,767]
constexpr int BLK  = 256;

__device__ __forceinline__ int swz(int x) {
    const int seg = x >> 5;
    const int off = x & 31;
    return (seg << 5) | ((off + ((seg & 7) << 2)) & 31);
}

// one 4-col step for 16 outputs: quads qa..qe hold K words [B-4 .. B+15]
// (qa = highest quad [B+12..B+15], qe = lowest [B-4..B-1]); k = p-s+4 in [1,19]
__device__ __forceinline__ void step64(const float4 iv,
    const float4 qa, const float4 qb, const float4 qc,
    const float4 qd, const float4 qe, float* __restrict__ acc)
{
    const float* A = (const float*)&qa;
    const float* Bq = (const float*)&qb;
    const float* C = (const float*)&qc;
    const float* D = (const float*)&qd;
    const float* E = (const float*)&qe;
    const float* I = (const float*)&iv;
#pragma unroll
    for (int p = 0; p < 16; ++p) {
#pragma unroll
        for (int s = 0; s < 4; ++s) {
            const int k = p - s + 4;  // compile-time after unroll
            const float kv = (k < 4)  ? E[k]
                           : (k < 8)  ? D[k - 4]
                           : (k < 12) ? C[k - 8]
                           : (k < 16) ? Bq[k - 12]
                                      : A[k - 16];
            acc[p] = fmaf(I[s], kv, acc[p]);
        }
    }
}

__global__ __launch_bounds__(BLK, 4) void corr3(
    const float* __restrict__ img, const float* __restrict__ pos,
    float* __restrict__ out)
{
    __shared__ float Ks[NR * KROW];
    __shared__ float red[4][OW];

    const int i   = blockIdx.x;
    const int ii0 = blockIdx.y * NR;
    const int tid = threadIdx.x;

    const float pos0 = pos[0];
    const float pos1 = pos[1];

    // ---- build swizzled K rows: word t holds 1/(dx^2 + (t-512+pos1)^2)
    for (int rg = 0; rg < NR; ++rg) {
        const float dx  = (float)(i - (ii0 + rg)) + pos0;
        const float dx2 = dx * dx;
        for (int x = tid; x < KROW; x += BLK) {
            const float dy = (float)(x - 512) + pos1;
            Ks[rg * KROW + swz(x)] = 1.0f / (dx2 + dy * dy);
        }
    }
    __syncthreads();

    const int M  = tid & 15;        // lane-in-group: owns j = 16M+p
    const int G  = tid >> 4;        // group 0..15
    const int rg = G >> 1;          // img row group 0..7
    const int h  = G & 1;           // col half
    const int row = ii0 + rg;

    const float*  kb = &Ks[rg * KROW];
    const float4* ip = (const float4*)(img + row * W + 256 * h);

    const int B0 = 16 * M + 512 - 256 * h;

    // prologue: slot s holds quad starting at word B0+12-4s (s = 0..6)
    float4 Q0 = *(const float4*)&kb[swz(B0 + 12)];
    float4 Q1 = *(const float4*)&kb[swz(B0 +  8)];
    float4 Q2 = *(const float4*)&kb[swz(B0 +  4)];
    float4 Q3 = *(const float4*)&kb[swz(B0     )];
    float4 Q4 = *(const float4*)&kb[swz(B0 -  4)];
    float4 Q5 = *(const float4*)&kb[swz(B0 -  8)];
    float4 Q6 = *(const float4*)&kb[swz(B0 - 12)];
    float4 Q7;

    float acc[16];
#pragma unroll
    for (int p = 0; p < 16; ++p) acc[p] = 0.f;

    float4 ivA = ip[0], ivB;
    int wrd = B0 - 16;   // word of the quad read at step ci (used at ci+3)
    int ci  = 0;

    // step ci: uses slots ci..ci+4 (mod 8); reads into slot ci+7 (mod 8)
#define S1(QA, QB, QC, QD, QE, QT, IVC, IVN)                                  \
    do {                                                                      \
        IVN = ip[ci < 63 ? ci + 1 : 63];                                      \
        const int trc = wrd > 0 ? wrd : 0;                                    \
        QT = *(const float4*)&kb[swz(trc)];                                   \
        wrd -= 4;                                                             \
        step64(IVC, QA, QB, QC, QD, QE, acc);                                 \
        ++ci;                                                                 \
    } while (0)

#pragma unroll 1
    for (int t8 = 0; t8 < 8; ++t8) {
        S1(Q0, Q1, Q2, Q3, Q4, Q7, ivA, ivB);
        S1(Q1, Q2, Q3, Q4, Q5, Q0, ivB, ivA);
        S1(Q2, Q3, Q4, Q5, Q6, Q1, ivA, ivB);
        S1(Q3, Q4, Q5, Q6, Q7, Q2, ivB, ivA);
        S1(Q4, Q5, Q6, Q7, Q0, Q3, ivA, ivB);
        S1(Q5, Q6, Q7, Q0, Q1, Q4, ivB, ivA);
        S1(Q6, Q7, Q0, Q1, Q2, Q5, ivA, ivB);
        S1(Q7, Q0, Q1, Q2, Q3, Q6, ivB, ivA);
    }
#undef S1

    // ---- fold the wave's 4 groups (2 rows x 2 halves share the same j map)
#pragma unroll
    for (int p = 0; p < 16; ++p) {
        acc[p] += __shfl_xor(acc[p], 16);
        acc[p] += __shfl_xor(acc[p], 32);
    }

    const int wv = tid >> 6;
    if ((tid & 48) == 0) {
#pragma unroll
        for (int p = 0; p < 16; ++p)
            red[wv][16 * M + p] = acc[p];
    }
    __syncthreads();

    {
        const int j = tid;  // BLK == OW
        const float s = red[0][j] + red[1][j] + red[2][j] + red[3][j];
        atomicAdd(&out[i * OW + j], s);
    }
}

extern "C" void kernel_launch(void* const* d_in, const int* in_sizes, int n_in,
                              void* d_out, int out_size, void* d_ws, size_t ws_size,
                              hipStream_t stream) {
    const float* img = (const float*)d_in[0];
    const float* pos = (const float*)d_in[1];
    float* out = (float*)d_out;

    hipMemsetAsync(out, 0, (size_t)out_size * sizeof(float), stream);

    dim3 grid(OH, H / NR);   // 32 x 32 = 1024 blocks, 4/CU co-resident
    corr3<<<grid, BLK, 0, stream>>>(img, pos, out);
}